// Round 12
// baseline (825.359 us; speedup 1.0000x reference)
//
#include <hip/hip_runtime.h>

typedef _Float16 f16;
typedef _Float16 f16x2 __attribute__((ext_vector_type(2)));
typedef _Float16 f16x4 __attribute__((ext_vector_type(4)));

#define VOCAB 100000
#define DIM 128
#define BATCH 262144
#define NEG 5

#define NBLOCK 2048
#define NTHREADS 256

#define F32_TABLE_BYTES ((size_t)VOCAB * DIM * 4)   // 51.2 MB
#define PLANE_BYTES     ((size_t)VOCAB * 128)       // 12.8 MB (half-row fp16 plane)

// workspace layout
#define OFF_ACC   ((size_t)0)                        // 8 floats
#define OFF_F32C  ((size_t)256)                      // fp32 copies: iembC, oembC
#define OFF_F16   (OFF_F32C + 2 * F32_TABLE_BYTES)   // 4 fp16 planes
#define WS_FULL   (OFF_F16 + 4 * PLANE_BYTES)        // ~153.6 MB
#define WS_SPLIT  (256 + 4 * PLANE_BYTES)            // ~51.2 MB (no f32 copy)

// log(1 + exp(x)); |x| <~ 0.04 here so exp(-|x|) ~ 1: no cancellation risk.
__device__ __forceinline__ float softplus_fast(float x) {
    return fmaxf(x, 0.0f) + __logf(1.0f + __expf(-fabsf(x)));
}

__device__ __forceinline__ float fdot2h(f16x2 a, f16x2 b, float c) {
#if __has_builtin(__builtin_amdgcn_fdot2)
    return __builtin_amdgcn_fdot2(a, b, c, false);
#else
    return c + (float)a[0] * (float)b[0] + (float)a[1] * (float)b[1];
#endif
}

__device__ __forceinline__ float dot16h(uint4 a0, uint4 a1, uint4 b0, uint4 b1) {
    union { uint4 u; f16x2 h[4]; } A0, A1, B0, B1;
    A0.u = a0; A1.u = a1; B0.u = b0; B1.u = b1;
    float s0 = 0.0f, s1 = 0.0f;
    #pragma unroll
    for (int i = 0; i < 4; ++i) {
        s0 = fdot2h(A0.h[i], B0.h[i], s0);
        s1 = fdot2h(A1.h[i], B1.h[i], s1);
    }
    return s0 + s1;
}

__device__ __forceinline__ float dot4f(float4 a, float4 b) {
    return a.x * b.x + a.y * b.y + a.z * b.z + a.w * b.w;
}

__global__ void ns_init_kernel(float* acc) {
    #pragma unroll
    for (int i = 0; i < 8; ++i) acc[i] = 0.0f;
}

// ---- d2d copy of both fp32 tables into d_ws (streaming) ----
__global__ __launch_bounds__(256) void ns_copy_f32_kernel(
    const float* __restrict__ iemb, const float* __restrict__ oemb,
    float* __restrict__ iembC, float* __restrict__ oembC)
{
    const int n4 = VOCAB * DIM / 4;
    int i = blockIdx.x * blockDim.x + threadIdx.x;
    const int stride = gridDim.x * blockDim.x;
    for (; i < n4; i += stride) {
        reinterpret_cast<float4*>(iembC)[i] = reinterpret_cast<const float4*>(iemb)[i];
        reinterpret_cast<float4*>(oembC)[i] = reinterpret_cast<const float4*>(oemb)[i];
    }
}

// ---- fp32 -> fp16 conversion into SPLIT planes (lo dims 0..63, hi 64..127) ----
__global__ __launch_bounds__(256) void ns_convert_split_kernel(
    const float* __restrict__ iemb, const float* __restrict__ oemb,
    f16* __restrict__ ilo, f16* __restrict__ ihi,
    f16* __restrict__ olo, f16* __restrict__ ohi)
{
    const int n4 = VOCAB * DIM / 4;    // float4 chunks; 32 per row
    int i = blockIdx.x * blockDim.x + threadIdx.x;
    const int stride = gridDim.x * blockDim.x;
    for (; i < n4; i += stride) {
        const int w = i >> 5;
        const int p = i & 31;
        float4 a = reinterpret_cast<const float4*>(iemb)[i];
        f16x4 ha = {(f16)a.x, (f16)a.y, (f16)a.z, (f16)a.w};
        float4 b = reinterpret_cast<const float4*>(oemb)[i];
        f16x4 hb = {(f16)b.x, (f16)b.y, (f16)b.z, (f16)b.w};
        if (p < 16) {
            reinterpret_cast<f16x4*>(ilo)[w * 16 + p] = ha;
            reinterpret_cast<f16x4*>(olo)[w * 16 + p] = hb;
        } else {
            reinterpret_cast<f16x4*>(ihi)[w * 16 + (p - 16)] = ha;
            reinterpret_cast<f16x4*>(ohi)[w * 16 + (p - 16)] = hb;
        }
    }
}

// ---- R4 fp32 loss, parameterized table+acc pointers (identical codegen A/B) ----
__global__ __launch_bounds__(256) void ns_loss_f32_kernel(
    const int* __restrict__ tgt, const int* __restrict__ ctx,
    const int* __restrict__ negw,
    const float* __restrict__ iemb, const float* __restrict__ oemb,
    float* __restrict__ accp)
{
    const int tid = threadIdx.x;
    const int r   = tid & 7;
    const int grp = tid >> 3;
    const int e0  = blockIdx.x * 32 + grp;
    const int estride = gridDim.x * 32;

    float pos_acc = 0.0f, neg_acc = 0.0f;
    for (int e = e0; e < BATCH; e += estride) {
        const int tw = tgt[e];
        const int cw = ctx[e];
        const float4* tp = reinterpret_cast<const float4*>(iemb + (size_t)tw * DIM) + r * 4;
        const float4 t0 = tp[0], t1 = tp[1], t2 = tp[2], t3 = tp[3];
        const float4* cp = reinterpret_cast<const float4*>(oemb + (size_t)cw * DIM) + r * 4;
        float dp = dot4f(t0, cp[0]) + dot4f(t1, cp[1]) + dot4f(t2, cp[2]) + dot4f(t3, cp[3]);
        float dn[NEG];
        #pragma unroll
        for (int j = 0; j < NEG; ++j) {
            const int nw = negw[e * NEG + j];
            const float4* np_ = reinterpret_cast<const float4*>(oemb + (size_t)nw * DIM) + r * 4;
            dn[j] = dot4f(t0, np_[0]) + dot4f(t1, np_[1]) + dot4f(t2, np_[2]) + dot4f(t3, np_[3]);
        }
        #pragma unroll
        for (int m = 4; m >= 1; m >>= 1) {
            dp += __shfl_xor(dp, m, 64);
            #pragma unroll
            for (int j = 0; j < NEG; ++j) dn[j] += __shfl_xor(dn[j], m, 64);
        }
        pos_acc += softplus_fast(-dp);
        float s = 0.0f;
        #pragma unroll
        for (int j = 0; j < NEG; ++j) s += softplus_fast(dn[j]);
        neg_acc += s;
    }
    #pragma unroll
    for (int m = 32; m >= 1; m >>= 1) {
        pos_acc += __shfl_xor(pos_acc, m, 64);
        neg_acc += __shfl_xor(neg_acc, m, 64);
    }
    if ((tid & 63) == 0) {
        atomicAdd(&accp[0], pos_acc);
        atomicAdd(&accp[1], neg_acc);
    }
}

// ---- fp16 SPLIT-PLANE loss: row halves 12.8 MB apart (kills 256B contiguity) ----
__global__ __launch_bounds__(256) void ns_loss_h_split_kernel(
    const int* __restrict__ tgt, const int* __restrict__ ctx,
    const int* __restrict__ negw,
    const f16* __restrict__ ilo, const f16* __restrict__ ihi,
    const f16* __restrict__ olo, const f16* __restrict__ ohi,
    float* __restrict__ accp)
{
    const int tid = threadIdx.x;
    const int r   = tid & 7;        // 16B chunk within a 128B half-row
    const int grp = tid >> 3;
    const int e0  = blockIdx.x * 32 + grp;
    const int estride = gridDim.x * 32;

    float pos_acc = 0.0f, neg_acc = 0.0f;
    for (int e = e0; e < BATCH; e += estride) {
        const int tw = tgt[e];
        const int cw = ctx[e];

        const uint4 t_lo = reinterpret_cast<const uint4*>(ilo)[(size_t)tw * 8 + r];
        const uint4 t_hi = reinterpret_cast<const uint4*>(ihi)[(size_t)tw * 8 + r];
        const uint4 c_lo = reinterpret_cast<const uint4*>(olo)[(size_t)cw * 8 + r];
        const uint4 c_hi = reinterpret_cast<const uint4*>(ohi)[(size_t)cw * 8 + r];
        float dp = dot16h(t_lo, t_hi, c_lo, c_hi);

        float dn[NEG];
        #pragma unroll
        for (int j = 0; j < NEG; ++j) {
            const int nw = negw[e * NEG + j];
            const uint4 n_lo = reinterpret_cast<const uint4*>(olo)[(size_t)nw * 8 + r];
            const uint4 n_hi = reinterpret_cast<const uint4*>(ohi)[(size_t)nw * 8 + r];
            dn[j] = dot16h(t_lo, t_hi, n_lo, n_hi);
        }

        #pragma unroll
        for (int m = 4; m >= 1; m >>= 1) {
            dp += __shfl_xor(dp, m, 64);
            #pragma unroll
            for (int j = 0; j < NEG; ++j) dn[j] += __shfl_xor(dn[j], m, 64);
        }
        pos_acc += softplus_fast(-dp);
        float s = 0.0f;
        #pragma unroll
        for (int j = 0; j < NEG; ++j) s += softplus_fast(dn[j]);
        neg_acc += s;
    }
    #pragma unroll
    for (int m = 32; m >= 1; m >>= 1) {
        pos_acc += __shfl_xor(pos_acc, m, 64);
        neg_acc += __shfl_xor(neg_acc, m, 64);
    }
    if ((tid & 63) == 0) {
        atomicAdd(&accp[0], pos_acc);
        atomicAdd(&accp[1], neg_acc);
    }
}

__global__ void ns_finalize_kernel(const float* __restrict__ acc, float* __restrict__ out) {
    out[0] = acc[0] * (1.0f / ((float)BATCH * 8.0f));
    out[1] = acc[1] * (1.0f / ((float)BATCH * (float)NEG * 8.0f));
}

extern "C" void kernel_launch(void* const* d_in, const int* in_sizes, int n_in,
                              void* d_out, int out_size, void* d_ws, size_t ws_size,
                              hipStream_t stream) {
    const int*   tgt  = (const int*)d_in[0];
    const int*   ctx  = (const int*)d_in[1];
    const int*   negw = (const int*)d_in[2];
    const float* iemb = (const float*)d_in[3];
    const float* oemb = (const float*)d_in[4];
    float* out = (float*)d_out;

    char* ws = (char*)d_ws;
    float* acc = (float*)(ws + OFF_ACC);       // [0,1] real  [2,3] f32-dws dummy  [4,5] f16-split dummy

    ns_init_kernel<<<1, 1, 0, stream>>>(acc);

    // real output: R4 fp32 kernel gathering from d_in (anchor, ~147 us)
    ns_loss_f32_kernel<<<NBLOCK, NTHREADS, 0, stream>>>(tgt, ctx, negw, iemb, oemb, acc);

    if (ws_size >= WS_FULL) {
        // Experiment A: identical f32 kernel, tables copied into d_ws (dummy acc)
        float* iembC = (float*)(ws + OFF_F32C);
        float* oembC = (float*)(ws + OFF_F32C + F32_TABLE_BYTES);
        ns_copy_f32_kernel<<<NBLOCK, NTHREADS, 0, stream>>>(iemb, oemb, iembC, oembC);
        ns_loss_f32_kernel<<<NBLOCK, NTHREADS, 0, stream>>>(tgt, ctx, negw, iembC, oembC, acc + 2);

        // Experiment B: fp16 split-plane layout (dummy acc)
        f16* ilo = (f16*)(ws + OFF_F16);
        f16* ihi = (f16*)(ws + OFF_F16 + PLANE_BYTES);
        f16* olo = (f16*)(ws + OFF_F16 + 2 * PLANE_BYTES);
        f16* ohi = (f16*)(ws + OFF_F16 + 3 * PLANE_BYTES);
        ns_convert_split_kernel<<<NBLOCK, NTHREADS, 0, stream>>>(iemb, oemb, ilo, ihi, olo, ohi);
        ns_loss_h_split_kernel<<<NBLOCK, NTHREADS, 0, stream>>>(tgt, ctx, negw, ilo, ihi, olo, ohi, acc + 4);
    } else if (ws_size >= WS_SPLIT) {
        // reduced experiment: split-plane only, planes right after acc
        f16* ilo = (f16*)(ws + 256);
        f16* ihi = (f16*)(ws + 256 + PLANE_BYTES);
        f16* olo = (f16*)(ws + 256 + 2 * PLANE_BYTES);
        f16* ohi = (f16*)(ws + 256 + 3 * PLANE_BYTES);
        ns_convert_split_kernel<<<NBLOCK, NTHREADS, 0, stream>>>(iemb, oemb, ilo, ihi, olo, ohi);
        ns_loss_h_split_kernel<<<NBLOCK, NTHREADS, 0, stream>>>(tgt, ctx, negw, ilo, ihi, olo, ohi, acc + 4);
    }

    ns_finalize_kernel<<<1, 1, 0, stream>>>(acc, out);
}